// Round 5
// baseline (512.607 us; speedup 1.0000x reference)
//
#include <hip/hip_runtime.h>

#define NN 262144

typedef __attribute__((ext_vector_type(8))) short short8;
typedef __attribute__((ext_vector_type(4))) float f32x4;

__device__ __forceinline__ unsigned short f2b(float x){
  union { float f; unsigned int u; } c; c.f = x;
  unsigned int u = c.u;
  unsigned int r = (u + 0x7FFFu + ((u >> 16) & 1u)) >> 16;
  return (unsigned short)r;
}

// ---------------- precompute: Wfold = Wm@Wu, bias_r = K*bm@Wu + bu ----------------
__global__ void prep1(const float* __restrict__ Wm, const float* __restrict__ Wu,
                      const float* __restrict__ bm, const float* __restrict__ bu,
                      float* __restrict__ Wfold, float* __restrict__ bias_r)
{
  int j = threadIdx.x;          // 0..127
  int i = blockIdx.x;           // 0..128 (128 => bias row)
  if (i < 128){
    float s = 0.f;
    for (int k = 0; k < 128; ++k) s += Wm[i*128 + k] * Wu[k*128 + j];
    Wfold[i*128 + j] = s;
  } else {
    float s = bu[j];
    for (int m = 0; m < 128; ++m) s += 8.0f * bm[m] * Wu[m*128 + j];
    bias_r[j] = s;
  }
}

// ---------------- precompute: transposed, padded, bf16 weights + folded biases ----
__global__ void prep2(const float* __restrict__ W0, const float* __restrict__ b0,
                      const float* __restrict__ W1, const float* __restrict__ b1,
                      const float* __restrict__ W2, const float* __restrict__ b2,
                      const float* __restrict__ W3, const float* __restrict__ b3,
                      const float* __restrict__ Wfold, const float* __restrict__ bias_r,
                      unsigned short* __restrict__ W1t, unsigned short* __restrict__ W2t,
                      unsigned short* __restrict__ W3t, unsigned short* __restrict__ W4t,
                      float* __restrict__ c0p, float* __restrict__ b1p,
                      float* __restrict__ b2p, float* __restrict__ b3p)
{
  int g = blockIdx.x * 256 + threadIdx.x;
  if (g < 40960){                       // W1t: c = g%160, k = g/160
    int c = g % 160, k = g / 160;
    float v = 0.f;
    if (c < 132){
      if (k < 128) v = W0[k*132 + c];
      else {
        int i = k - 128; float s = 0.f;
        for (int m = 0; m < 128; ++m) s += Wfold[i*128 + m] * W0[(128 + m)*132 + c];
        v = s;
      }
    }
    W1t[c*256 + k] = f2b(v);
  } else if (g < 66560){                // W2t
    int idx = g - 40960; int c = idx % 160, k = idx / 160;
    float v = (c < 132 && k < 132) ? W1[k*132 + c] : 0.f;
    W2t[c*160 + k] = f2b(v);
  } else if (g < 92160){                // W3t
    int idx = g - 66560; int c = idx % 160, k = idx / 160;
    float v = (c < 132 && k < 132) ? W2[k*132 + c] : 0.f;
    W3t[c*160 + k] = f2b(v);
  } else if (g < 112640){               // W4t [128][160]
    int idx = g - 92160; int c = idx & 127, k = idx >> 7;
    float v = (k < 132) ? W3[k*128 + c] : 0.f;
    W4t[c*160 + k] = f2b(v);
  } else if (g < 113248){               // biases
    int idx = g - 112640;
    if (idx < 160){
      int c = idx; float v = 0.f;
      if (c < 132){
        float s = b0[c];
        for (int k = 0; k < 128; ++k) s += bias_r[k] * W0[(128 + k)*132 + c];
        v = s;
      }
      c0p[c] = v;
    } else if (idx < 320){ int c = idx - 160; b1p[c] = (c < 132) ? b1[c] : 0.f; }
    else if (idx < 480){ int c = idx - 320; b2p[c] = (c < 132) ? b2[c] : 0.f; }
    else               { int c = idx - 480; b3p[c] = b3[c]; }
  }
}

// ---------------- grand-fused persistent kernel ----------------
// 512 blocks x 512 threads (8 waves), 8 node-tiles of 64 per block.
// LDS (ushort units): ACT @0 [64][256] swizzled (32 KiB); HA @16384 [64][168];
// HB @27136 [64][168].  Total 74 KiB.
// Wave split: wodd=(w&1) -> node rows {ntA+lr, ntA+32+lr}; fgrp=w>>1 -> feature
// tiles ct = fgrp+4*fi (guard ct<NT).  Swapped-operand MFMA (proven R2):
// D[feat][node], epilogue: node row = ntA+n2*32+lr, feat = ct*16+lg*4+r.

template<int KD, bool SWZ, int NT, int FI, bool RELU>
__device__ __forceinline__ void layer_t(const unsigned short* __restrict__ smem, int rbase,
                                        int wodd, int fgrp, int lr, int lg,
                                        const unsigned short* __restrict__ Wt,
                                        const float* __restrict__ bias,
                                        unsigned short* __restrict__ smw, int wbase)
{
  const int ntA = wodd * 16;
  constexpr int KS = KD / 32;
  short8 b[2][KS];
  #pragma unroll
  for (int ks = 0; ks < KS; ++ks){
    const int colu = ks*32 + lg*8;
    if (SWZ){
      int cb = colu * 2;
      int rA = ntA + lr, rB = ntA + 32 + lr;
      b[0][ks] = *(const short8*)&smem[rbase + ((rA*512 + (cb ^ ((rA & 7) << 4))) >> 1)];
      b[1][ks] = *(const short8*)&smem[rbase + ((rB*512 + (cb ^ ((rB & 7) << 4))) >> 1)];
    } else {
      b[0][ks] = *(const short8*)&smem[rbase + (ntA + lr)*168 + colu];
      b[1][ks] = *(const short8*)&smem[rbase + (ntA + 32 + lr)*168 + colu];
    }
  }
  #pragma unroll
  for (int fi = 0; fi < FI; ++fi){
    const int ct = fgrp + 4*fi;
    if (ct < NT){
      short8 wf[KS];
      #pragma unroll
      for (int ks = 0; ks < KS; ++ks)
        wf[ks] = *(const short8*)&Wt[(ct*16 + lr)*KD + ks*32 + lg*8];
      f32x4 a0 = (f32x4){0.f,0.f,0.f,0.f};
      f32x4 a1 = (f32x4){0.f,0.f,0.f,0.f};
      #pragma unroll
      for (int ks = 0; ks < KS; ++ks){
        a0 = __builtin_amdgcn_mfma_f32_16x16x32_bf16(wf[ks], b[0][ks], a0, 0, 0, 0);
        a1 = __builtin_amdgcn_mfma_f32_16x16x32_bf16(wf[ks], b[1][ks], a1, 0, 0, 0);
      }
      float4 bv = *(const float4*)&bias[ct*16 + lg*4];
      {
        float v0 = a0[0]+bv.x, v1 = a0[1]+bv.y, v2 = a0[2]+bv.z, v3 = a0[3]+bv.w;
        if (RELU){ v0=fmaxf(v0,0.f); v1=fmaxf(v1,0.f); v2=fmaxf(v2,0.f); v3=fmaxf(v3,0.f); }
        ushort4 p; p.x=f2b(v0); p.y=f2b(v1); p.z=f2b(v2); p.w=f2b(v3);
        *(ushort4*)&smw[wbase + (ntA + lr)*168 + ct*16 + lg*4] = p;
      }
      {
        float v0 = a1[0]+bv.x, v1 = a1[1]+bv.y, v2 = a1[2]+bv.z, v3 = a1[3]+bv.w;
        if (RELU){ v0=fmaxf(v0,0.f); v1=fmaxf(v1,0.f); v2=fmaxf(v2,0.f); v3=fmaxf(v3,0.f); }
        ushort4 p; p.x=f2b(v0); p.y=f2b(v1); p.z=f2b(v2); p.w=f2b(v3);
        *(ushort4*)&smw[wbase + (ntA + 32 + lr)*168 + ct*16 + lg*4] = p;
      }
    }
  }
}

__device__ __forceinline__ void layer_out4(const unsigned short* __restrict__ smem, int rbase,
                                           int wodd, int fgrp, int lr, int lg,
                                           const unsigned short* __restrict__ Wt,
                                           const float* __restrict__ bias,
                                           float* __restrict__ out, long n0)
{
  const int ntA = wodd * 16;
  short8 b[2][5];
  #pragma unroll
  for (int ks = 0; ks < 5; ++ks){
    const int colu = ks*32 + lg*8;
    b[0][ks] = *(const short8*)&smem[rbase + (ntA + lr)*168 + colu];
    b[1][ks] = *(const short8*)&smem[rbase + (ntA + 32 + lr)*168 + colu];
  }
  #pragma unroll
  for (int fi = 0; fi < 2; ++fi){
    const int ct = fgrp + 4*fi;            // 0..7, always valid
    short8 wf[5];
    #pragma unroll
    for (int ks = 0; ks < 5; ++ks)
      wf[ks] = *(const short8*)&Wt[(ct*16 + lr)*160 + ks*32 + lg*8];
    f32x4 a0 = (f32x4){0.f,0.f,0.f,0.f};
    f32x4 a1 = (f32x4){0.f,0.f,0.f,0.f};
    #pragma unroll
    for (int ks = 0; ks < 5; ++ks){
      a0 = __builtin_amdgcn_mfma_f32_16x16x32_bf16(wf[ks], b[0][ks], a0, 0, 0, 0);
      a1 = __builtin_amdgcn_mfma_f32_16x16x32_bf16(wf[ks], b[1][ks], a1, 0, 0, 0);
    }
    float4 bv = *(const float4*)&bias[ct*16 + lg*4];
    float4 o0; o0.x=a0[0]+bv.x; o0.y=a0[1]+bv.y; o0.z=a0[2]+bv.z; o0.w=a0[3]+bv.w;
    float4 o1; o1.x=a1[0]+bv.x; o1.y=a1[1]+bv.y; o1.z=a1[2]+bv.z; o1.w=a1[3]+bv.w;
    *(float4*)&out[(n0 + ntA + lr)*128 + ct*16 + lg*4]      = o0;
    *(float4*)&out[(n0 + ntA + 32 + lr)*128 + ct*16 + lg*4] = o1;
  }
}

__global__ __launch_bounds__(512, 2) void fused_all(
    const float* __restrict__ sig, const float* __restrict__ comp,
    const unsigned short* __restrict__ W1t, const unsigned short* __restrict__ W2t,
    const unsigned short* __restrict__ W3t, const unsigned short* __restrict__ W4t,
    const float* __restrict__ c0p, const float* __restrict__ b1p,
    const float* __restrict__ b2p, const float* __restrict__ b3p,
    float* __restrict__ out)
{
  __shared__ unsigned short smem[37888];   // 74 KiB
  const int ACT = 0, HA = 16384, HB = 27136;

  const int tid  = threadIdx.x;
  const int l    = tid & 63;
  const int lr   = l & 15, lg = l >> 4;
  const int w    = tid >> 6;
  const int wodd = w & 1, fgrp = w >> 1;

  const float4* __restrict__ compv = (const float4*)comp;
  const float4* __restrict__ sigv  = (const float4*)sig;

  for (int t = 0; t < 8; ++t){
    const long n0 = ((long)blockIdx.x * 8 + t) * 64;

    // ---- stage: comp-sum (8 streams) + sig -> bf16 -> swizzled ACT ----
    #pragma unroll
    for (int p = 0; p < 4; ++p){
      int idx = tid + 512*p;               // float4 idx in [64][32] tile
      int row = idx >> 5, c4 = idx & 31;
      long base = (n0 + row)*32 + c4;
      float4 sg = sigv[base];
      float4 s  = compv[base];
      #pragma unroll
      for (int k = 1; k < 8; ++k){
        float4 v = compv[(long)k*(NN*32) + base];
        s.x += v.x; s.y += v.y; s.z += v.z; s.w += v.w;
      }
      int cb = c4*8, mask = (row & 7) << 4;
      ushort4 ps; ps.x=f2b(sg.x); ps.y=f2b(sg.y); ps.z=f2b(sg.z); ps.w=f2b(sg.w);
      ushort4 pm; pm.x=f2b(s.x);  pm.y=f2b(s.y);  pm.z=f2b(s.z);  pm.w=f2b(s.w);
      *(ushort4*)&smem[ACT + ((row*512 + (cb ^ mask)) >> 1)]         = ps;
      *(ushort4*)&smem[ACT + ((row*512 + ((256 + cb) ^ mask)) >> 1)] = pm;
    }
    __syncthreads();

    // ---- 4-layer MFMA chain ----
    layer_t<256, true,  10, 3, true>(smem, ACT, wodd, fgrp, lr, lg, W1t, c0p, smem, HA);
    __syncthreads();
    layer_t<160, false, 10, 3, true>(smem, HA,  wodd, fgrp, lr, lg, W2t, b1p, smem, HB);
    __syncthreads();
    layer_t<160, false, 10, 3, true>(smem, HB,  wodd, fgrp, lr, lg, W3t, b2p, smem, HA);
    __syncthreads();
    layer_out4(smem, HA, wodd, fgrp, lr, lg, W4t, b3p, out, n0);
    // no barrier needed here: next stage writes ACT (not HA); the post-stage
    // barrier separates everyone's L4 reads of HA from next L1 writes of HA.
  }
}

// ---------------- launch ----------------
extern "C" void kernel_launch(void* const* d_in, const int* in_sizes, int n_in,
                              void* d_out, int out_size, void* d_ws, size_t ws_size,
                              hipStream_t stream)
{
  const float* sig  = (const float*)d_in[0];
  const float* comp = (const float*)d_in[1];
  const float* Wm   = (const float*)d_in[2];
  const float* bm   = (const float*)d_in[3];
  const float* Wu   = (const float*)d_in[4];
  const float* bu   = (const float*)d_in[5];
  const float* W0   = (const float*)d_in[6];
  const float* b0   = (const float*)d_in[7];
  const float* W1   = (const float*)d_in[8];
  const float* b1   = (const float*)d_in[9];
  const float* W2   = (const float*)d_in[10];
  const float* b2   = (const float*)d_in[11];
  const float* W3   = (const float*)d_in[12];
  const float* b3   = (const float*)d_in[13];

  char* ws = (char*)d_ws;
  float* Wfold  = (float*)(ws + 0);          // 65536
  float* bias_r = (float*)(ws + 65536);      // 512
  float* c0p    = (float*)(ws + 66048);      // 640
  float* b1p    = (float*)(ws + 66688);      // 640
  float* b2p    = (float*)(ws + 67328);      // 640
  float* b3p    = (float*)(ws + 67968);      // 512
  unsigned short* W1t = (unsigned short*)(ws + 69632);    // 81920
  unsigned short* W2t = (unsigned short*)(ws + 151552);   // 51200
  unsigned short* W3t = (unsigned short*)(ws + 202752);   // 51200
  unsigned short* W4t = (unsigned short*)(ws + 253952);   // 40960

  prep1<<<129, 128, 0, stream>>>(Wm, Wu, bm, bu, Wfold, bias_r);
  prep2<<<443, 256, 0, stream>>>(W0, b0, W1, b1, W2, b2, W3, b3, Wfold, bias_r,
                                 W1t, W2t, W3t, W4t, c0p, b1p, b2p, b3p);
  fused_all<<<512, 512, 0, stream>>>(sig, comp, W1t, W2t, W3t, W4t,
                                     c0p, b1p, b2p, b3p, (float*)d_out);
}

// Round 6
// 502.093 us; speedup vs baseline: 1.0209x; 1.0209x over previous
//
#include <hip/hip_runtime.h>

#define NN 262144

typedef __attribute__((ext_vector_type(8))) short short8;
typedef __attribute__((ext_vector_type(4))) float f32x4;

__device__ __forceinline__ unsigned short f2b(float x){
  union { float f; unsigned int u; } c; c.f = x;
  unsigned int u = c.u;
  unsigned int r = (u + 0x7FFFu + ((u >> 16) & 1u)) >> 16;
  return (unsigned short)r;
}

// ---------------- precompute: Wfold = Wm@Wu, bias_r = K*bm@Wu + bu ----------------
__global__ void prep1(const float* __restrict__ Wm, const float* __restrict__ Wu,
                      const float* __restrict__ bm, const float* __restrict__ bu,
                      float* __restrict__ Wfold, float* __restrict__ bias_r)
{
  int j = threadIdx.x;          // 0..127
  int i = blockIdx.x;           // 0..128 (128 => bias row)
  if (i < 128){
    float s = 0.f;
    for (int k = 0; k < 128; ++k) s += Wm[i*128 + k] * Wu[k*128 + j];
    Wfold[i*128 + j] = s;
  } else {
    float s = bu[j];
    for (int m = 0; m < 128; ++m) s += 8.0f * bm[m] * Wu[m*128 + j];
    bias_r[j] = s;
  }
}

// ---------------- precompute: transposed, padded, bf16 weights + folded biases ----
__global__ void prep2(const float* __restrict__ W0, const float* __restrict__ b0,
                      const float* __restrict__ W1, const float* __restrict__ b1,
                      const float* __restrict__ W2, const float* __restrict__ b2,
                      const float* __restrict__ W3, const float* __restrict__ b3,
                      const float* __restrict__ Wfold, const float* __restrict__ bias_r,
                      unsigned short* __restrict__ W1t, unsigned short* __restrict__ W2t,
                      unsigned short* __restrict__ W3t, unsigned short* __restrict__ W4t,
                      float* __restrict__ c0p, float* __restrict__ b1p,
                      float* __restrict__ b2p, float* __restrict__ b3p)
{
  int g = blockIdx.x * 256 + threadIdx.x;
  if (g < 40960){                       // W1t: c = g%160, k = g/160
    int c = g % 160, k = g / 160;
    float v = 0.f;
    if (c < 132){
      if (k < 128) v = W0[k*132 + c];
      else {
        int i = k - 128; float s = 0.f;
        for (int m = 0; m < 128; ++m) s += Wfold[i*128 + m] * W0[(128 + m)*132 + c];
        v = s;
      }
    }
    W1t[c*256 + k] = f2b(v);
  } else if (g < 66560){                // W2t
    int idx = g - 40960; int c = idx % 160, k = idx / 160;
    float v = (c < 132 && k < 132) ? W1[k*132 + c] : 0.f;
    W2t[c*160 + k] = f2b(v);
  } else if (g < 92160){                // W3t
    int idx = g - 66560; int c = idx % 160, k = idx / 160;
    float v = (c < 132 && k < 132) ? W2[k*132 + c] : 0.f;
    W3t[c*160 + k] = f2b(v);
  } else if (g < 112640){               // W4t [128][160]
    int idx = g - 92160; int c = idx & 127, k = idx >> 7;
    float v = (k < 132) ? W3[k*128 + c] : 0.f;
    W4t[c*160 + k] = f2b(v);
  } else if (g < 113248){               // biases
    int idx = g - 112640;
    if (idx < 160){
      int c = idx; float v = 0.f;
      if (c < 132){
        float s = b0[c];
        for (int k = 0; k < 128; ++k) s += bias_r[k] * W0[(128 + k)*132 + c];
        v = s;
      }
      c0p[c] = v;
    } else if (idx < 320){ int c = idx - 160; b1p[c] = (c < 132) ? b1[c] : 0.f; }
    else if (idx < 480){ int c = idx - 320; b2p[c] = (c < 132) ? b2[c] : 0.f; }
    else               { int c = idx - 480; b3p[c] = b3[c]; }
  }
}

// ---------------- wave-autonomous fused kernel (no barriers) ----------------
// Each wave owns 16 nodes end-to-end in a private 8 KiB LDS patch
// [16 rows][256 bf16], row stride 512 B, XOR swizzle byte ^= (row&7)<<4.
// Layers run in-place (per-wave DS ops are in-order; all B-frag reads are
// issued before epilogue writes).  Fragment layouts identical to proven R2.

__device__ __forceinline__ int pidx(int row, int colByte){
  return (row*512 + (colByte ^ ((row & 7) << 4))) >> 1;   // ushort index
}

template<int KD, int NT, bool RELU>
__device__ __forceinline__ void layer_p(unsigned short* __restrict__ patch,
                                        int n, int lg,
                                        const unsigned short* __restrict__ Wt,
                                        const float* __restrict__ bias)
{
  constexpr int KS = KD / 32;
  short8 bf[KS];
  #pragma unroll
  for (int ks = 0; ks < KS; ++ks)
    bf[ks] = *(const short8*)&patch[pidx(n, ks*64 + lg*16)];

  #pragma unroll
  for (int c = 0; c < NT; c += 2){
    short8 wa[KS], wb[KS];
    #pragma unroll
    for (int ks = 0; ks < KS; ++ks){
      wa[ks] = *(const short8*)&Wt[(c*16 + n)*KD + ks*32 + lg*8];
      wb[ks] = *(const short8*)&Wt[((c+1)*16 + n)*KD + ks*32 + lg*8];
    }
    f32x4 aa = (f32x4){0.f,0.f,0.f,0.f};
    f32x4 ab = (f32x4){0.f,0.f,0.f,0.f};
    #pragma unroll
    for (int ks = 0; ks < KS; ++ks){
      aa = __builtin_amdgcn_mfma_f32_16x16x32_bf16(wa[ks], bf[ks], aa, 0, 0, 0);
      ab = __builtin_amdgcn_mfma_f32_16x16x32_bf16(wb[ks], bf[ks], ab, 0, 0, 0);
    }
    float4 va = *(const float4*)&bias[c*16 + lg*4];
    float4 vb = *(const float4*)&bias[(c+1)*16 + lg*4];
    float a0=aa[0]+va.x, a1=aa[1]+va.y, a2=aa[2]+va.z, a3=aa[3]+va.w;
    float b0=ab[0]+vb.x, b1=ab[1]+vb.y, b2=ab[2]+vb.z, b3=ab[3]+vb.w;
    if (RELU){
      a0=fmaxf(a0,0.f); a1=fmaxf(a1,0.f); a2=fmaxf(a2,0.f); a3=fmaxf(a3,0.f);
      b0=fmaxf(b0,0.f); b1=fmaxf(b1,0.f); b2=fmaxf(b2,0.f); b3=fmaxf(b3,0.f);
    }
    ushort4 pa; pa.x=f2b(a0); pa.y=f2b(a1); pa.z=f2b(a2); pa.w=f2b(a3);
    ushort4 pb; pb.x=f2b(b0); pb.y=f2b(b1); pb.z=f2b(b2); pb.w=f2b(b3);
    *(ushort4*)&patch[pidx(n, c*32 + lg*8)]     = pa;   // colByte=(c*16+lg*4)*2
    *(ushort4*)&patch[pidx(n, (c+1)*32 + lg*8)] = pb;
  }
}

__global__ __launch_bounds__(256, 3) void fused_wave(
    const float* __restrict__ sig, const float* __restrict__ comp,
    const unsigned short* __restrict__ W1t, const unsigned short* __restrict__ W2t,
    const unsigned short* __restrict__ W3t, const unsigned short* __restrict__ W4t,
    const float* __restrict__ c0p, const float* __restrict__ b1p,
    const float* __restrict__ b2p, const float* __restrict__ b3p,
    float* __restrict__ out)
{
  __shared__ unsigned short smem[16384];   // 32 KiB = 4 waves x 8 KiB
  const int tid = threadIdx.x;
  const int l   = tid & 63;
  const int n   = l & 15, lg = l >> 4;
  const int w   = tid >> 6;
  unsigned short* patch = smem + w*4096;
  const long n0 = ((long)blockIdx.x * 4 + w) * 16;

  const float4* __restrict__ sigv  = (const float4*)sig;
  const float4* __restrict__ compv = (const float4*)comp;

  // ---- stage: sig -> patch cols 0..127 ----
  #pragma unroll
  for (int j = 0; j < 8; ++j){
    int slot = l + 64*j;                  // 0..511: row = slot>>5, c4 = slot&31
    int row = slot >> 5, c4 = slot & 31;
    float4 v = sigv[(n0 + row)*32 + c4];
    ushort4 p; p.x=f2b(v.x); p.y=f2b(v.y); p.z=f2b(v.z); p.w=f2b(v.w);
    *(ushort4*)&patch[pidx(row, c4*8)] = p;
  }
  // ---- stage: sum_k comp -> patch cols 128..255 ----
  #pragma unroll
  for (int j = 0; j < 8; ++j){
    int slot = l + 64*j;
    int row = slot >> 5, c4 = slot & 31;
    long base = (n0 + row)*32 + c4;
    float4 s = compv[base];
    #pragma unroll
    for (int k = 1; k < 8; ++k){
      float4 v = compv[(long)k*(NN*32) + base];
      s.x += v.x; s.y += v.y; s.z += v.z; s.w += v.w;
    }
    ushort4 p; p.x=f2b(s.x); p.y=f2b(s.y); p.z=f2b(s.z); p.w=f2b(s.w);
    *(ushort4*)&patch[pidx(row, 256 + c4*8)] = p;
  }

  // ---- 3 hidden layers, in-place in the patch ----
  layer_p<256, 10, true>(patch, n, lg, W1t, c0p);
  layer_p<160, 10, true>(patch, n, lg, W2t, b1p);
  layer_p<160, 10, true>(patch, n, lg, W3t, b2p);

  // ---- output layer: KD=160, 8 ct tiles, float4 -> global ----
  {
    short8 bf[5];
    #pragma unroll
    for (int ks = 0; ks < 5; ++ks)
      bf[ks] = *(const short8*)&patch[pidx(n, ks*64 + lg*16)];
    #pragma unroll
    for (int c = 0; c < 8; c += 2){
      short8 wa[5], wb[5];
      #pragma unroll
      for (int ks = 0; ks < 5; ++ks){
        wa[ks] = *(const short8*)&W4t[(c*16 + n)*160 + ks*32 + lg*8];
        wb[ks] = *(const short8*)&W4t[((c+1)*16 + n)*160 + ks*32 + lg*8];
      }
      f32x4 aa = (f32x4){0.f,0.f,0.f,0.f};
      f32x4 ab = (f32x4){0.f,0.f,0.f,0.f};
      #pragma unroll
      for (int ks = 0; ks < 5; ++ks){
        aa = __builtin_amdgcn_mfma_f32_16x16x32_bf16(wa[ks], bf[ks], aa, 0, 0, 0);
        ab = __builtin_amdgcn_mfma_f32_16x16x32_bf16(wb[ks], bf[ks], ab, 0, 0, 0);
      }
      float4 va = *(const float4*)&b3p[c*16 + lg*4];
      float4 vb = *(const float4*)&b3p[(c+1)*16 + lg*4];
      float4 oa; oa.x=aa[0]+va.x; oa.y=aa[1]+va.y; oa.z=aa[2]+va.z; oa.w=aa[3]+va.w;
      float4 ob; ob.x=ab[0]+vb.x; ob.y=ab[1]+vb.y; ob.z=ab[2]+vb.z; ob.w=ab[3]+vb.w;
      *(float4*)&out[(n0 + n)*128 + c*16 + lg*4]     = oa;
      *(float4*)&out[(n0 + n)*128 + (c+1)*16 + lg*4] = ob;
    }
  }
}

// ---------------- launch ----------------
extern "C" void kernel_launch(void* const* d_in, const int* in_sizes, int n_in,
                              void* d_out, int out_size, void* d_ws, size_t ws_size,
                              hipStream_t stream)
{
  const float* sig  = (const float*)d_in[0];
  const float* comp = (const float*)d_in[1];
  const float* Wm   = (const float*)d_in[2];
  const float* bm   = (const float*)d_in[3];
  const float* Wu   = (const float*)d_in[4];
  const float* bu   = (const float*)d_in[5];
  const float* W0   = (const float*)d_in[6];
  const float* b0   = (const float*)d_in[7];
  const float* W1   = (const float*)d_in[8];
  const float* b1   = (const float*)d_in[9];
  const float* W2   = (const float*)d_in[10];
  const float* b2   = (const float*)d_in[11];
  const float* W3   = (const float*)d_in[12];
  const float* b3   = (const float*)d_in[13];

  char* ws = (char*)d_ws;
  float* Wfold  = (float*)(ws + 0);          // 65536
  float* bias_r = (float*)(ws + 65536);      // 512
  float* c0p    = (float*)(ws + 66048);      // 640
  float* b1p    = (float*)(ws + 66688);      // 640
  float* b2p    = (float*)(ws + 67328);      // 640
  float* b3p    = (float*)(ws + 67968);      // 512
  unsigned short* W1t = (unsigned short*)(ws + 69632);    // 81920
  unsigned short* W2t = (unsigned short*)(ws + 151552);   // 51200
  unsigned short* W3t = (unsigned short*)(ws + 202752);   // 51200
  unsigned short* W4t = (unsigned short*)(ws + 253952);   // 40960

  prep1<<<129, 128, 0, stream>>>(Wm, Wu, bm, bu, Wfold, bias_r);
  prep2<<<443, 256, 0, stream>>>(W0, b0, W1, b1, W2, b2, W3, b3, Wfold, bias_r,
                                 W1t, W2t, W3t, W4t, c0p, b1p, b2p, b3p);
  fused_wave<<<4096, 256, 0, stream>>>(sig, comp, W1t, W2t, W3t, W4t,
                                       c0p, b1p, b2p, b3p, (float*)d_out);
}